// Round 2
// baseline (221.239 us; speedup 1.0000x reference)
//
#include <hip/hip_runtime.h>
#include <hip/hip_bf16.h>
#include <stdint.h>
#include <stddef.h>

typedef __bf16 bf16_t;
typedef __bf16 v8bf __attribute__((ext_vector_type(8)));
typedef __bf16 v4bf __attribute__((ext_vector_type(4)));
typedef float  v4f  __attribute__((ext_vector_type(4)));

#define L_SEQ 2048
#define DM    1024
#define NH    16
#define LOG2E 1.44269504088896340736f

// ---- async global->LDS, 16B per lane. LDS dest is wave-uniform base;
// HW writes lane i at base + 16*i. Global address is per-lane (we exploit
// this to XOR-swizzle the LDS tile layout without breaking contiguity).
__device__ __forceinline__ void async_cp16(const void* g, void* l) {
  __builtin_amdgcn_global_load_lds(
      (__attribute__((address_space(1))) void*)(g),
      (__attribute__((address_space(3))) void*)(l),
      16, 0, 0);
}

__device__ __forceinline__ v4f mfma16(v8bf a, v8bf b, v4f c) {
  return __builtin_amdgcn_mfma_f32_16x16x32_bf16(a, b, c, 0, 0, 0);
}

// ============ fp32 -> bf16 elementwise convert (q, k, v) ============
__global__ void k_cvt3(const float* __restrict__ a0, const float* __restrict__ a1,
                       const float* __restrict__ a2,
                       bf16_t* __restrict__ o0, bf16_t* __restrict__ o1,
                       bf16_t* __restrict__ o2, int n4)
{
  const float* src = (blockIdx.z == 0) ? a0 : (blockIdx.z == 1) ? a1 : a2;
  bf16_t*      dst = (blockIdx.z == 0) ? o0 : (blockIdx.z == 1) ? o1 : o2;
  for (int i = blockIdx.x * blockDim.x + threadIdx.x; i < n4;
       i += gridDim.x * blockDim.x) {
    v4f x = ((const v4f*)src)[i];
    v4bf y;
    y[0] = (bf16_t)x[0]; y[1] = (bf16_t)x[1];
    y[2] = (bf16_t)x[2]; y[3] = (bf16_t)x[3];
    ((v4bf*)dst)[i] = y;
  }
}

// ============ fp32 [R][C] -> bf16 [C][R] transposed weight convert ============
__global__ void k_cvt_transpose_w(
    const float* __restrict__ w0, const float* __restrict__ w1,
    const float* __restrict__ w2, const float* __restrict__ w3,
    bf16_t* __restrict__ o0, bf16_t* __restrict__ o1,
    bf16_t* __restrict__ o2, bf16_t* __restrict__ o3)
{
  const int z = blockIdx.z;
  const float* in = (z == 0) ? w0 : (z == 1) ? w1 : (z == 2) ? w2 : w3;
  bf16_t*     out = (z == 0) ? o0 : (z == 1) ? o1 : (z == 2) ? o2 : o3;
  __shared__ float t[64 * 65];      // stride 65 dwords -> conflict-free
  const int tid = threadIdx.x;
  const int r0 = blockIdx.y * 64, c0 = blockIdx.x * 64;
#pragma unroll
  for (int p = 0; p < 16; ++p) {
    const int idx = p * 256 + tid;
    const int r = idx >> 6, c = idx & 63;
    t[r * 65 + c] = in[(size_t)(r0 + r) * DM + c0 + c];
  }
  __syncthreads();
#pragma unroll
  for (int p = 0; p < 16; ++p) {
    const int idx = p * 256 + tid;
    const int c = idx >> 6, r = idx & 63;
    out[(size_t)(c0 + c) * DM + r0 + r] = (bf16_t)t[r * 65 + c];
  }
}

// ============ bf16 [R][C] -> bf16 [C][R] transpose (for V) ============
__global__ void k_transpose(const bf16_t* __restrict__ in, bf16_t* __restrict__ out,
                            int R, int Cc)
{
  __shared__ bf16_t t[64 * 66];
  const int tid = threadIdx.x;
  const int r0 = blockIdx.y * 64, c0 = blockIdx.x * 64;
#pragma unroll
  for (int p = 0; p < 16; ++p) {
    const int idx = p * 256 + tid;
    const int r = idx >> 6, c = idx & 63;
    t[r * 66 + c] = in[(size_t)(r0 + r) * Cc + c0 + c];
  }
  __syncthreads();
#pragma unroll
  for (int p = 0; p < 16; ++p) {
    const int idx = p * 256 + tid;
    const int c = idx >> 6, r = idx & 63;
    out[(size_t)(c0 + c) * R + r0 + r] = t[r * 66 + c];
  }
}

// ============ GEMM: C[M,N] = A[M,K] @ Bt[N,K]^T + bias[N] ============
// 128x128 tile, BK=32, 4 waves (2x2 of 64x64). LDS 16B chunks XOR-swizzled:
// phys_chunk = logical_chunk ^ ((row>>1)&3) -> frag ds_read_b128 2-way (free).
template <typename OutT>
__device__ __forceinline__ void gemm_bt_body(
    const bf16_t* __restrict__ A, const bf16_t* __restrict__ Bt,
    const float* __restrict__ bias, OutT* __restrict__ C,
    int M, int N, int K, int bx, int by)
{
  __shared__ __align__(16) bf16_t As[128 * 32];
  __shared__ __align__(16) bf16_t Bs[128 * 32];
  const int tid  = threadIdx.x;
  const int w    = tid >> 6;
  const int lane = tid & 63;
  const int l16  = lane & 15;
  const int q4   = lane >> 4;
  const int m0   = by * 128, n0 = bx * 128;
  const int wm   = (w >> 1) * 64, wn = (w & 1) * 64;

  v4f acc[4][4];
#pragma unroll
  for (int i = 0; i < 4; ++i)
#pragma unroll
    for (int j = 0; j < 4; ++j) {
      v4f z = {0.f, 0.f, 0.f, 0.f};
      acc[i][j] = z;
    }

  for (int k0 = 0; k0 < K; k0 += 32) {
#pragma unroll
    for (int c = 0; c < 2; ++c) {
      const int rbase = 32 * w + 16 * c;
      const int row   = rbase + (lane >> 2);           // 4 chunks (16B) per row
      const int q     = (lane & 3) ^ ((row >> 1) & 3); // logical chunk fetched
      async_cp16(A  + (size_t)(m0 + row) * K + k0 + q * 8, As + rbase * 32);
      async_cp16(Bt + (size_t)(n0 + row) * K + k0 + q * 8, Bs + rbase * 32);
    }
    __syncthreads();   // compiler drains vmcnt before s_barrier

    v8bf af[4], bf_[4];
#pragma unroll
    for (int mi = 0; mi < 4; ++mi) {
      const int row = wm + mi * 16 + l16;
      const int qq  = q4 ^ ((row >> 1) & 3);
      af[mi] = *(const v8bf*)(As + row * 32 + qq * 8);
    }
#pragma unroll
    for (int ni = 0; ni < 4; ++ni) {
      const int row = wn + ni * 16 + l16;
      const int qq  = q4 ^ ((row >> 1) & 3);
      bf_[ni] = *(const v8bf*)(Bs + row * 32 + qq * 8);
    }
#pragma unroll
    for (int mi = 0; mi < 4; ++mi)
#pragma unroll
      for (int ni = 0; ni < 4; ++ni)
        acc[mi][ni] = mfma16(af[mi], bf_[ni], acc[mi][ni]);
    __syncthreads();
  }

  // epilogue: C/D layout col=lane&15, row=(lane>>4)*4+reg  (m89/m91 verified)
  float bv[4];
#pragma unroll
  for (int ni = 0; ni < 4; ++ni) bv[ni] = bias[n0 + wn + ni * 16 + l16];
#pragma unroll
  for (int mi = 0; mi < 4; ++mi) {
#pragma unroll
    for (int r = 0; r < 4; ++r) {
      const int row = m0 + wm + mi * 16 + q4 * 4 + r;
#pragma unroll
      for (int ni = 0; ni < 4; ++ni) {
        const int col = n0 + wn + ni * 16 + l16;
        C[(size_t)row * N + col] = (OutT)(acc[mi][ni][r] + bv[ni]);
      }
    }
  }
}

__global__ __launch_bounds__(256, 2) void k_gemm_f32out(
    const bf16_t* __restrict__ A, const bf16_t* __restrict__ Bt,
    const float* __restrict__ bias, float* __restrict__ C,
    int M, int N, int K)
{
  gemm_bt_body<float>(A, Bt, bias, C, M, N, K, blockIdx.x, blockIdx.y);
}

__global__ __launch_bounds__(256, 2) void k_gemm_qkv(
    const bf16_t* __restrict__ q, const bf16_t* __restrict__ k,
    const bf16_t* __restrict__ v,
    const bf16_t* __restrict__ wqt, const bf16_t* __restrict__ wkt,
    const bf16_t* __restrict__ wvt,
    const float* __restrict__ bq, const float* __restrict__ bk,
    const float* __restrict__ bv,
    bf16_t* __restrict__ Qp, bf16_t* __restrict__ Kp, bf16_t* __restrict__ Vp)
{
  const int z = blockIdx.z;
  const bf16_t* A    = (z == 0) ? q   : (z == 1) ? k   : v;
  const bf16_t* Bt   = (z == 0) ? wqt : (z == 1) ? wkt : wvt;
  const float*  bias = (z == 0) ? bq  : (z == 1) ? bk  : bv;
  bf16_t*       C    = (z == 0) ? Qp  : (z == 1) ? Kp  : Vp;
  gemm_bt_body<bf16_t>(A, Bt, bias, C, L_SEQ, DM, DM, blockIdx.x, blockIdx.y);
}

// ============ flash attention ============
// block = (head, 64 q-rows), 4 waves x 16 q-rows; Bc=64 keys/iter.
// Qs/Ks: [row][d] (opA/opB for QK^T). Vs: [d][j] from pre-transposed V (opB
// for PV). Ps: [qrow][j] stride 72 (opA for PV), wave-private rows.
// 64-col tiles: 8 chunks/row, phys_chunk = logical ^ (row&7) -> conflict-free.
__global__ __launch_bounds__(256, 2) void k_attn(
    const bf16_t* __restrict__ Qp,   // [L, DM]
    const bf16_t* __restrict__ Kp,   // [L, DM]
    const bf16_t* __restrict__ Vt,   // [DM, L]
    bf16_t* __restrict__ AO)         // [L, DM]
{
  const int h  = blockIdx.y;
  const int q0 = blockIdx.x * 64;
  const int tid = threadIdx.x, w = tid >> 6, lane = tid & 63;
  const int l16 = lane & 15, q4 = lane >> 4;

  __shared__ __align__(16) bf16_t Qs[64 * 64];
  __shared__ __align__(16) bf16_t Ks[64 * 64];
  __shared__ __align__(16) bf16_t Vs[64 * 64];
  __shared__ __align__(16) bf16_t Ps[64 * 72];

  // stage Q tile once: wave w rows [16w,16w+16), 8 rows per 16B-call
#pragma unroll
  for (int c = 0; c < 2; ++c) {
    const int rbase = 16 * w + 8 * c;
    const int row = rbase + (lane >> 3);
    const int q   = (lane & 7) ^ (row & 7);
    async_cp16(Qp + (size_t)(q0 + row) * DM + h * 64 + q * 8, Qs + rbase * 64);
  }

  float mrow[4], lrow[4];
  v4f o[4];
#pragma unroll
  for (int r = 0; r < 4; ++r) { mrow[r] = -1e30f; lrow[r] = 0.f; }
#pragma unroll
  for (int d = 0; d < 4; ++d) { v4f z = {0.f,0.f,0.f,0.f}; o[d] = z; }

  for (int j0 = 0; j0 < L_SEQ; j0 += 64) {
#pragma unroll
    for (int c = 0; c < 2; ++c) {
      const int rbase = 16 * w + 8 * c;
      const int row = rbase + (lane >> 3);
      const int q   = (lane & 7) ^ (row & 7);
      async_cp16(Kp + (size_t)(j0 + row) * DM + h * 64 + q * 8, Ks + rbase * 64);
      async_cp16(Vt + (size_t)(h * 64 + row) * L_SEQ + j0 + q * 8, Vs + rbase * 64);
    }
    __syncthreads();

    // S = (Q K^T) * 1/sqrt(64)
    v4f s[4];
#pragma unroll
    for (int nf = 0; nf < 4; ++nf) {
      v4f a0 = {0.f,0.f,0.f,0.f};
#pragma unroll
      for (int ks = 0; ks < 2; ++ks) {
        const int rowa = 16 * w + l16;
        const int qa = (ks * 4 + q4) ^ (rowa & 7);
        v8bf a = *(const v8bf*)(Qs + rowa * 64 + qa * 8);
        const int rowb = nf * 16 + l16;
        const int qb = (ks * 4 + q4) ^ (rowb & 7);
        v8bf b = *(const v8bf*)(Ks + rowb * 64 + qb * 8);
        a0 = mfma16(a, b, a0);
      }
      s[nf] = a0 * 0.125f;
    }

    // online softmax per row (rows q4*4+r of this wave's 16-block;
    // each row is spread over the 16 lanes sharing q4)
    float pp[4][4];
    float al[4];
#pragma unroll
    for (int r = 0; r < 4; ++r) {
      float mx = fmaxf(fmaxf(s[0][r], s[1][r]), fmaxf(s[2][r], s[3][r]));
#pragma unroll
      for (int off = 1; off < 16; off <<= 1)
        mx = fmaxf(mx, __shfl_xor(mx, off, 64));
      const float mn = fmaxf(mrow[r], mx);
      al[r] = exp2f((mrow[r] - mn) * LOG2E);
      float rs = 0.f;
#pragma unroll
      for (int nf = 0; nf < 4; ++nf) {
        const float p = exp2f((s[nf][r] - mn) * LOG2E);
        pp[nf][r] = p;
        rs += p;
      }
#pragma unroll
      for (int off = 1; off < 16; off <<= 1)
        rs += __shfl_xor(rs, off, 64);
      lrow[r] = lrow[r] * al[r] + rs;
      mrow[r] = mn;
    }
#pragma unroll
    for (int d = 0; d < 4; ++d)
#pragma unroll
      for (int r = 0; r < 4; ++r) o[d][r] *= al[r];

    // P -> LDS (C-layout -> A-operand layout round-trip; wave-private rows)
#pragma unroll
    for (int r = 0; r < 4; ++r)
#pragma unroll
      for (int nf = 0; nf < 4; ++nf)
        Ps[(16 * w + q4 * 4 + r) * 72 + nf * 16 + l16] = (bf16_t)pp[nf][r];

    // O += P V
#pragma unroll
    for (int d = 0; d < 4; ++d) {
#pragma unroll
      for (int ks = 0; ks < 2; ++ks) {
        const int rowa = 16 * w + l16;
        v8bf a = *(const v8bf*)(Ps + rowa * 72 + ks * 32 + q4 * 8);
        const int rowb = d * 16 + l16;
        const int qb = (ks * 4 + q4) ^ (rowb & 7);
        v8bf b = *(const v8bf*)(Vs + rowb * 64 + qb * 8);
        o[d] = mfma16(a, b, o[d]);
      }
    }
    __syncthreads();
  }

  // epilogue: O /= l, write [L, DM] with heads as column slices
#pragma unroll
  for (int r = 0; r < 4; ++r) {
    const float inv = 1.f / lrow[r];
    const int row = q0 + 16 * w + q4 * 4 + r;
#pragma unroll
    for (int d = 0; d < 4; ++d)
      AO[(size_t)row * DM + h * 64 + d * 16 + l16] = (bf16_t)(o[d][r] * inv);
  }
}

// ============ launcher ============
extern "C" void kernel_launch(void* const* d_in, const int* in_sizes, int n_in,
                              void* d_out, int out_size, void* d_ws, size_t ws_size,
                              hipStream_t stream)
{
  const float* q  = (const float*)d_in[0];
  const float* k  = (const float*)d_in[1];
  const float* v  = (const float*)d_in[2];
  const float* wq = (const float*)d_in[3];
  const float* bq = (const float*)d_in[4];
  const float* wk = (const float*)d_in[5];
  const float* bk = (const float*)d_in[6];
  const float* wv = (const float*)d_in[7];
  const float* bv = (const float*)d_in[8];
  const float* wo = (const float*)d_in[9];
  const float* bo = (const float*)d_in[10];
  float* out = (float*)d_out;

  bf16_t* ws  = (bf16_t*)d_ws;
  bf16_t* Qb  = ws;                       // bf16 copies of q,k,v [2048,1024]
  bf16_t* Kb  = Qb  + (size_t)L_SEQ * DM;
  bf16_t* Vb  = Kb  + (size_t)L_SEQ * DM;
  bf16_t* Qp  = Vb  + (size_t)L_SEQ * DM; // projected Q/K/V
  bf16_t* Kp  = Qp  + (size_t)L_SEQ * DM;
  bf16_t* Vp  = Kp  + (size_t)L_SEQ * DM;
  bf16_t* Vtr = Vp  + (size_t)L_SEQ * DM; // [1024,2048]
  bf16_t* AO  = Vtr + (size_t)L_SEQ * DM;
  bf16_t* Wqt = AO  + (size_t)L_SEQ * DM; // [1024,1024] each, transposed bf16
  bf16_t* Wkt = Wqt + (size_t)DM * DM;
  bf16_t* Wvt = Wkt + (size_t)DM * DM;
  bf16_t* Wot = Wvt + (size_t)DM * DM;
  // total ws use: 8*4MB + 4*2MB = 40MB

  // 1. fp32 -> bf16 for q, k, v
  k_cvt3<<<dim3(512, 1, 3), 256, 0, stream>>>(q, k, v, Qb, Kb, Vb,
                                              (L_SEQ * DM) / 4);
  // 2. weights: fp32 [K,N] -> bf16 [N,K]
  k_cvt_transpose_w<<<dim3(16, 16, 4), 256, 0, stream>>>(wq, wk, wv, wo,
                                                         Wqt, Wkt, Wvt, Wot);
  // 3. Q/K/V projections
  k_gemm_qkv<<<dim3(8, 16, 3), 256, 0, stream>>>(Qb, Kb, Vb, Wqt, Wkt, Wvt,
                                                 bq, bk, bv, Qp, Kp, Vp);
  // 4. V -> V^T  ([2048,1024] -> [1024,2048])
  k_transpose<<<dim3(16, 32), 256, 0, stream>>>(Vp, Vtr, L_SEQ, DM);
  // 5. fused attention
  k_attn<<<dim3(32, 16), 256, 0, stream>>>(Qp, Kp, Vtr, AO);
  // 6. output projection (fp32 out)
  k_gemm_f32out<<<dim3(8, 16), 256, 0, stream>>>(AO, Wot, bo, out,
                                                 L_SEQ, DM, DM);
}

// Round 3
// 188.007 us; speedup vs baseline: 1.1768x; 1.1768x over previous
//
#include <hip/hip_runtime.h>
#include <hip/hip_bf16.h>
#include <stdint.h>
#include <stddef.h>

typedef __bf16 bf16_t;
typedef __bf16 v8bf __attribute__((ext_vector_type(8)));
typedef __bf16 v4bf __attribute__((ext_vector_type(4)));
typedef float  v4f  __attribute__((ext_vector_type(4)));

#define L_SEQ 2048
#define DM    1024
#define NH    16
#define LOG2E 1.44269504088896340736f
#define SCL   (0.125f * LOG2E)   // 1/sqrt(64) folded into exp2 argument

// async global->LDS, 16B/lane. LDS dest is wave-uniform base + 16*lane.
__device__ __forceinline__ void async_cp16(const void* g, void* l) {
  __builtin_amdgcn_global_load_lds(
      (__attribute__((address_space(1))) void*)(g),
      (__attribute__((address_space(3))) void*)(l),
      16, 0, 0);
}

__device__ __forceinline__ v4f mfma16(v8bf a, v8bf b, v4f c) {
  return __builtin_amdgcn_mfma_f32_16x16x32_bf16(a, b, c, 0, 0, 0);
}

// ============ prep: fp32->bf16 cvt of q,k,v (z=4..6) + transposed
// ============ bf16 weight convert (z=0..3), one launch
__global__ void k_prep(
    const float* __restrict__ q, const float* __restrict__ k,
    const float* __restrict__ v,
    const float* __restrict__ w0, const float* __restrict__ w1,
    const float* __restrict__ w2, const float* __restrict__ w3,
    bf16_t* __restrict__ Qb, bf16_t* __restrict__ Kb, bf16_t* __restrict__ Vb,
    bf16_t* __restrict__ o0, bf16_t* __restrict__ o1,
    bf16_t* __restrict__ o2, bf16_t* __restrict__ o3)
{
  const int z = blockIdx.z;
  const int tid = threadIdx.x;
  if (z < 4) {
    const float* in = (z == 0) ? w0 : (z == 1) ? w1 : (z == 2) ? w2 : w3;
    bf16_t*     out = (z == 0) ? o0 : (z == 1) ? o1 : (z == 2) ? o2 : o3;
    __shared__ float t[64 * 65];
    const int r0 = blockIdx.y * 64, c0 = blockIdx.x * 64;
#pragma unroll
    for (int p = 0; p < 16; ++p) {
      const int idx = p * 256 + tid;
      const int r = idx >> 6, c = idx & 63;
      t[r * 65 + c] = in[(size_t)(r0 + r) * DM + c0 + c];
    }
    __syncthreads();
#pragma unroll
    for (int p = 0; p < 16; ++p) {
      const int idx = p * 256 + tid;
      const int c = idx >> 6, r = idx & 63;
      out[(size_t)(c0 + c) * DM + r0 + r] = (bf16_t)t[r * 65 + c];
    }
  } else {
    const float* src = (z == 4) ? q : (z == 5) ? k : v;
    bf16_t*      dst = (z == 4) ? Qb : (z == 5) ? Kb : Vb;
    const int n4 = (L_SEQ * DM) / 4;
    const int base = (blockIdx.y * 16 + blockIdx.x) * 256 + tid;
#pragma unroll
    for (int i = base; i < n4; i += 16 * 16 * 256) {
      v4f x = ((const v4f*)src)[i];
      v4bf y;
      y[0] = (bf16_t)x[0]; y[1] = (bf16_t)x[1];
      y[2] = (bf16_t)x[2]; y[3] = (bf16_t)x[3];
      ((v4bf*)dst)[i] = y;
    }
  }
}

// ============ bf16 transpose (for V): out[C][R] = in[R][C]^T ============
__global__ void k_transpose(const bf16_t* __restrict__ in, bf16_t* __restrict__ out,
                            int R, int Cc)
{
  __shared__ bf16_t t[64 * 66];
  const int tid = threadIdx.x;
  const int r0 = blockIdx.y * 64, c0 = blockIdx.x * 64;
#pragma unroll
  for (int p = 0; p < 16; ++p) {
    const int idx = p * 256 + tid;
    const int r = idx >> 6, c = idx & 63;
    t[r * 66 + c] = in[(size_t)(r0 + r) * Cc + c0 + c];
  }
  __syncthreads();
#pragma unroll
  for (int p = 0; p < 16; ++p) {
    const int idx = p * 256 + tid;
    const int c = idx >> 6, r = idx & 63;
    out[(size_t)(c0 + c) * R + r0 + r] = t[r * 66 + c];
  }
}

// ============ GEMM: C[M,N] = A[M,K] @ Bt[N,K]^T + bias[N] ============
// 128(M)x64(N) tile, BK=64 double-buffered, 1 barrier/iter with post-barrier
// prefetch. 4 waves 2x2 -> wave-tile 64x32. 64-col LDS rows (8 chunks of
// 16B), phys_chunk = logical ^ (row&7).
template <typename OutT>
__device__ __forceinline__ void gemm_body(
    const bf16_t* __restrict__ A, const bf16_t* __restrict__ Bt,
    const float* __restrict__ bias, OutT* __restrict__ C,
    int M, int N, int K, int bx, int by)
{
  __shared__ __align__(16) bf16_t As[2][128 * 64];
  __shared__ __align__(16) bf16_t Bs[2][64 * 64];
  const int tid  = threadIdx.x;
  const int w    = tid >> 6;
  const int lane = tid & 63;
  const int l16  = lane & 15;
  const int q4   = lane >> 4;
  const int m0   = by * 128, n0 = bx * 64;
  const int wm   = (w >> 1) * 64, wn = (w & 1) * 32;

  v4f acc[4][2];
#pragma unroll
  for (int i = 0; i < 4; ++i)
#pragma unroll
    for (int j = 0; j < 2; ++j) {
      v4f z = {0.f, 0.f, 0.f, 0.f};
      acc[i][j] = z;
    }

  const int lr = lane >> 3;        // row within 8-row staging group
  const int lc = lane & 7;         // phys chunk slot

  // ---- stage one BK=64 stage into buf
  auto stage = [&](int k0, int buf) {
#pragma unroll
    for (int c = 0; c < 4; ++c) {               // As rows [32w, 32w+32)
      const int row = 32 * w + 8 * c + lr;
      const int q   = lc ^ (row & 7);
      async_cp16(A + (size_t)(m0 + row) * K + k0 + q * 8,
                 &As[buf][(32 * w + 8 * c) * 64]);
    }
#pragma unroll
    for (int c = 0; c < 2; ++c) {               // Bs rows [16w, 16w+16)
      const int row = 16 * w + 8 * c + lr;
      const int q   = lc ^ (row & 7);
      async_cp16(Bt + (size_t)(n0 + row) * K + k0 + q * 8,
                 &Bs[buf][(16 * w + 8 * c) * 64]);
    }
  };

  stage(0, 0);
  __syncthreads();

  const int nk = K >> 6;
  for (int kt = 0; kt < nk; ++kt) {
    if (kt + 1 < nk) stage((kt + 1) << 6, (kt + 1) & 1);
    const int buf = kt & 1;
#pragma unroll
    for (int ks = 0; ks < 2; ++ks) {
      v8bf af[4], bf_[2];
#pragma unroll
      for (int mi = 0; mi < 4; ++mi) {
        const int row = wm + mi * 16 + l16;
        const int pc  = (4 * ks + q4) ^ (row & 7);
        af[mi] = *(const v8bf*)(&As[buf][row * 64 + pc * 8]);
      }
#pragma unroll
      for (int ni = 0; ni < 2; ++ni) {
        const int row = wn + ni * 16 + l16;
        const int pc  = (4 * ks + q4) ^ (row & 7);
        bf_[ni] = *(const v8bf*)(&Bs[buf][row * 64 + pc * 8]);
      }
#pragma unroll
      for (int mi = 0; mi < 4; ++mi)
#pragma unroll
        for (int ni = 0; ni < 2; ++ni)
          acc[mi][ni] = mfma16(af[mi], bf_[ni], acc[mi][ni]);
    }
    __syncthreads();
  }

  // epilogue: C/D layout col=lane&15, row=(lane>>4)*4+reg
  float bv[2];
#pragma unroll
  for (int ni = 0; ni < 2; ++ni) bv[ni] = bias[n0 + wn + ni * 16 + l16];
#pragma unroll
  for (int mi = 0; mi < 4; ++mi) {
#pragma unroll
    for (int r = 0; r < 4; ++r) {
      const int row = m0 + wm + mi * 16 + q4 * 4 + r;
#pragma unroll
      for (int ni = 0; ni < 2; ++ni) {
        const int col = n0 + wn + ni * 16 + l16;
        C[(size_t)row * N + col] = (OutT)(acc[mi][ni][r] + bv[ni]);
      }
    }
  }
}

__global__ __launch_bounds__(256, 3) void k_gemm_f32out(
    const bf16_t* __restrict__ A, const bf16_t* __restrict__ Bt,
    const float* __restrict__ bias, float* __restrict__ C,
    int M, int N, int K)
{
  gemm_body<float>(A, Bt, bias, C, M, N, K, blockIdx.x, blockIdx.y);
}

__global__ __launch_bounds__(256, 3) void k_gemm_qkv(
    const bf16_t* __restrict__ q, const bf16_t* __restrict__ k,
    const bf16_t* __restrict__ v,
    const bf16_t* __restrict__ wqt, const bf16_t* __restrict__ wkt,
    const bf16_t* __restrict__ wvt,
    const float* __restrict__ bq, const float* __restrict__ bk,
    const float* __restrict__ bv,
    bf16_t* __restrict__ Qp, bf16_t* __restrict__ Kp, bf16_t* __restrict__ Vp)
{
  const int z = blockIdx.z;
  const bf16_t* A    = (z == 0) ? q   : (z == 1) ? k   : v;
  const bf16_t* Bt   = (z == 0) ? wqt : (z == 1) ? wkt : wvt;
  const float*  bias = (z == 0) ? bq  : (z == 1) ? bk  : bv;
  bf16_t*       C    = (z == 0) ? Qp  : (z == 1) ? Kp  : Vp;
  gemm_body<bf16_t>(A, Bt, bias, C, L_SEQ, DM, DM, blockIdx.x, blockIdx.y);
}

// ============ flash attention, S^T formulation ============
// block = (head, 64 q-rows), 4 waves x 16 q-rows; Bc=64 keys/iter, K/V
// double-buffered (1 barrier/iter, post-barrier prefetch).
// S^T[j][q] via MFMA(A=K rows, B=Q rows): lane then owns ONE q (=16w+l16)
// with 16 in-lane scores (j = nf*16 + q4*4 + r) -> in-lane softmax,
// cross-quad reduce = 2 shfl. O^T[d][q] via MFMA(A=V^T rows, B=P^T rows);
// P^T round-trip through wave-private Ps rows (no barrier).
__global__ __launch_bounds__(256, 2) void k_attn(
    const bf16_t* __restrict__ Qp,   // [L, DM]
    const bf16_t* __restrict__ Kp,   // [L, DM]
    const bf16_t* __restrict__ Vt,   // [DM, L]
    bf16_t* __restrict__ AO)         // [L, DM]
{
  const int h  = blockIdx.y;
  const int q0 = blockIdx.x * 64;
  const int tid = threadIdx.x, w = tid >> 6, lane = tid & 63;
  const int l16 = lane & 15, q4 = lane >> 4;
  const int lr = lane >> 3, lc = lane & 7;

  __shared__ __align__(16) bf16_t Qs[64 * 64];
  __shared__ __align__(16) bf16_t Ks[2][64 * 64];
  __shared__ __align__(16) bf16_t Vs[2][64 * 64];
  __shared__ __align__(16) bf16_t Ps[64 * 72];   // wave-private rows, j-contig

  auto stage_kv = [&](int j0, int buf) {
#pragma unroll
    for (int c = 0; c < 2; ++c) {
      const int row = 16 * w + 8 * c + lr;
      const int q   = lc ^ (row & 7);
      async_cp16(Kp + (size_t)(j0 + row) * DM + h * 64 + q * 8,
                 &Ks[buf][(16 * w + 8 * c) * 64]);
      async_cp16(Vt + (size_t)(h * 64 + row) * L_SEQ + j0 + q * 8,
                 &Vs[buf][(16 * w + 8 * c) * 64]);
    }
  };

  // stage Q (once) + first K/V tile
#pragma unroll
  for (int c = 0; c < 2; ++c) {
    const int row = 16 * w + 8 * c + lr;
    const int q   = lc ^ (row & 7);
    async_cp16(Qp + (size_t)(q0 + row) * DM + h * 64 + q * 8,
               &Qs[(16 * w + 8 * c) * 64]);
  }
  stage_kv(0, 0);
  __syncthreads();

  // hoisted Q B-frags (loop-invariant): n = q = 16w + l16
  v8bf bq[2];
  {
    const int rowq = 16 * w + l16;
#pragma unroll
    for (int ks = 0; ks < 2; ++ks) {
      const int pc = (4 * ks + q4) ^ (rowq & 7);
      bq[ks] = *(const v8bf*)(&Qs[rowq * 64 + pc * 8]);
    }
  }

  float m_run = -1e30f, l_run = 0.f;
  v4f od[4];
#pragma unroll
  for (int d = 0; d < 4; ++d) { v4f z = {0.f,0.f,0.f,0.f}; od[d] = z; }

  const int prow = 16 * w + l16;    // this lane's P^T row (wave-private)

  for (int jt = 0; jt < L_SEQ / 64; ++jt) {
    if (jt + 1 < L_SEQ / 64) stage_kv((jt + 1) * 64, (jt + 1) & 1);
    const int buf = jt & 1;

    // S^T = K Q^T : st[nf] holds S^T[j = nf*16+q4*4+r][q = 16w+l16]
    v4f st[4];
#pragma unroll
    for (int nf = 0; nf < 4; ++nf) {
      v4f a0 = {0.f, 0.f, 0.f, 0.f};
#pragma unroll
      for (int ks = 0; ks < 2; ++ks) {
        const int rowk = nf * 16 + l16;
        const int pc   = (4 * ks + q4) ^ (rowk & 7);
        v8bf ak = *(const v8bf*)(&Ks[buf][rowk * 64 + pc * 8]);
        a0 = mfma16(ak, bq[ks], a0);
      }
      st[nf] = a0;
    }

    // in-lane softmax over 16 scores (unscaled; 1/8 folded into exp arg)
    float mx = st[0][0];
#pragma unroll
    for (int nf = 0; nf < 4; ++nf)
#pragma unroll
      for (int r = 0; r < 4; ++r) mx = fmaxf(mx, st[nf][r]);
    mx = fmaxf(mx, __shfl_xor(mx, 16, 64));
    mx = fmaxf(mx, __shfl_xor(mx, 32, 64));
    const float mn    = fmaxf(m_run, mx);
    const float alpha = exp2f((m_run - mn) * SCL);
    const float mnS   = mn * SCL;
    m_run = mn;

    float ps = 0.f;
#pragma unroll
    for (int nf = 0; nf < 4; ++nf) {
      v4bf pb;
#pragma unroll
      for (int r = 0; r < 4; ++r) {
        const float p = exp2f(fmaf(st[nf][r], SCL, -mnS));
        ps += p;
        pb[r] = (bf16_t)p;
      }
      // P^T[q=prow][j = nf*16 + q4*4 .. +3]
      *(v4bf*)(&Ps[prow * 72 + nf * 16 + q4 * 4]) = pb;
    }
    l_run = l_run * alpha + ps;
#pragma unroll
    for (int d = 0; d < 4; ++d)
#pragma unroll
      for (int r = 0; r < 4; ++r) od[d][r] *= alpha;

    // O^T += V^T P : A = Vs rows (d), B = P^T rows (q) re-read j-contiguous
#pragma unroll
    for (int ks = 0; ks < 2; ++ks) {
      v8bf bp = *(const v8bf*)(&Ps[prow * 72 + ks * 32 + q4 * 8]);
#pragma unroll
      for (int dd = 0; dd < 4; ++dd) {
        const int rowv = dd * 16 + l16;
        const int pc   = (4 * ks + q4) ^ (rowv & 7);
        v8bf av = *(const v8bf*)(&Vs[buf][rowv * 64 + pc * 8]);
        od[dd] = mfma16(av, bp, od[dd]);
      }
    }
    __syncthreads();
  }

  // final l reduce across quads (each quad summed its own j-subset)
  l_run += __shfl_xor(l_run, 16, 64);
  l_run += __shfl_xor(l_run, 32, 64);
  const float inv = 1.f / l_run;

  // O^T[d][q] -> AO[q][h*64+d]; lane q = q0+16w+l16, d = dd*16+q4*4+r
  const int rowo = q0 + 16 * w + l16;
#pragma unroll
  for (int dd = 0; dd < 4; ++dd) {
    v4bf ob;
#pragma unroll
    for (int r = 0; r < 4; ++r) ob[r] = (bf16_t)(od[dd][r] * inv);
    *(v4bf*)(&AO[(size_t)rowo * DM + h * 64 + dd * 16 + q4 * 4]) = ob;
  }
}

// ============ launcher ============
extern "C" void kernel_launch(void* const* d_in, const int* in_sizes, int n_in,
                              void* d_out, int out_size, void* d_ws, size_t ws_size,
                              hipStream_t stream)
{
  const float* q  = (const float*)d_in[0];
  const float* k  = (const float*)d_in[1];
  const float* v  = (const float*)d_in[2];
  const float* wq = (const float*)d_in[3];
  const float* bq = (const float*)d_in[4];
  const float* wk = (const float*)d_in[5];
  const float* bk = (const float*)d_in[6];
  const float* wv = (const float*)d_in[7];
  const float* bv = (const float*)d_in[8];
  const float* wo = (const float*)d_in[9];
  const float* bo = (const float*)d_in[10];
  float* out = (float*)d_out;

  bf16_t* ws  = (bf16_t*)d_ws;
  bf16_t* Qb  = ws;
  bf16_t* Kb  = Qb  + (size_t)L_SEQ * DM;
  bf16_t* Vb  = Kb  + (size_t)L_SEQ * DM;
  bf16_t* Qp  = Vb  + (size_t)L_SEQ * DM;
  bf16_t* Kp  = Qp  + (size_t)L_SEQ * DM;
  bf16_t* Vp  = Kp  + (size_t)L_SEQ * DM;
  bf16_t* Vtr = Vp  + (size_t)L_SEQ * DM;
  bf16_t* AO  = Vtr + (size_t)L_SEQ * DM;
  bf16_t* Wqt = AO  + (size_t)L_SEQ * DM;
  bf16_t* Wkt = Wqt + (size_t)DM * DM;
  bf16_t* Wvt = Wkt + (size_t)DM * DM;
  bf16_t* Wot = Wvt + (size_t)DM * DM;

  // 1. fused prep: weight transpose-convert (z 0..3) + qkv convert (z 4..6)
  k_prep<<<dim3(16, 16, 7), 256, 0, stream>>>(q, k, v, wq, wk, wv, wo,
                                              Qb, Kb, Vb, Wqt, Wkt, Wvt, Wot);
  // 2. Q/K/V projections: 128x64 tiles -> 16x16x3 = 768 blocks
  k_gemm_qkv<<<dim3(16, 16, 3), 256, 0, stream>>>(Qb, Kb, Vb, Wqt, Wkt, Wvt,
                                                  bq, bk, bv, Qp, Kp, Vp);
  // 3. V -> V^T
  k_transpose<<<dim3(16, 32), 256, 0, stream>>>(Vp, Vtr, L_SEQ, DM);
  // 4. fused attention
  k_attn<<<dim3(32, 16), 256, 0, stream>>>(Qp, Kp, Vtr, AO);
  // 5. output projection (fp32 out): 256 blocks
  k_gemm_f32out<<<dim3(16, 16), 256, 0, stream>>>(AO, Wot, bo, out,
                                                  L_SEQ, DM, DM);
}